// Round 8
// baseline (489.543 us; speedup 1.0000x reference)
//
#include <hip/hip_runtime.h>
#include <hip/hip_bf16.h>

// GAT GNN: N=50000 nodes, E=800000 edges (+N self loops), C=64, H=4, L=3, NG=256
// R7: algebraic restructure — aggregation commutes with W:
//   als/ald = h @ (W·a)  [64,4 folded]          -> k_att (fp32 exact)
//   agg[n,h,:] = softmax-weighted sum of h[src]  -> k_agg gathers bf16 h rows
//                (128B/edge instead of 512B xh rows; xh never materialized)
//   h' = LN(agg_flat[N,256] @ Wfold[256,64] + bias) etc. -> k_post (MFMA,
//        bf16 A direct, hi/lo split B, fused LN/relu/residual, writes h+hb)

typedef __attribute__((__ext_vector_type__(8))) __bf16 bf16x8;
typedef __attribute__((__ext_vector_type__(4))) float f32x4;

__device__ __forceinline__ float wave_sum(float v) {
#pragma unroll
  for (int d = 32; d > 0; d >>= 1) v += __shfl_xor(v, d, 64);
  return v;
}
__device__ __forceinline__ float wave_max(float v) {
#pragma unroll
  for (int d = 32; d > 0; d >>= 1) v = fmaxf(v, __shfl_xor(v, d, 64));
  return v;
}
__device__ __forceinline__ float lrelu02(float v) { return fmaxf(v, 0.2f * v); }

__device__ __forceinline__ unsigned short f2bf(float f) {
  unsigned u = __float_as_uint(f);
  return (unsigned short)((u + 0x7fffu + ((u >> 16) & 1u)) >> 16);
}
__device__ __forceinline__ float bf2f(unsigned short s) {
  return __uint_as_float(((unsigned)s) << 16);
}

// h = relu(x @ W_in + b_in); also writes bf16 copy hb (gather source).
__global__ __launch_bounds__(256, 4) void k_input(const float* __restrict__ x,
    const float* __restrict__ Win, const float* __restrict__ bin,
    float* __restrict__ h, unsigned short* __restrict__ hb, int N)
{
  __shared__ float xs[64 * 32];
  int tid = threadIdx.x;
  int lane = tid & 63, wid = tid >> 6;
  int n0 = blockIdx.x * 64;
  int nrows = N - n0; if (nrows > 64) nrows = 64;
  {
    const float4* srcp = (const float4*)(x + (size_t)n0 * 32);
    float4* dstp = (float4*)xs;
    for (int i = tid; i < nrows * 8; i += 256) dstp[i] = srcp[i];
  }
  float wreg[32];
#pragma unroll
  for (int k = 0; k < 32; ++k) wreg[k] = Win[k * 64 + lane];
  float bv = bin[lane];
  __syncthreads();
  int nbeg = wid * 16;
  int nlim = nbeg + 16; if (nlim > nrows) nlim = nrows;
  for (int nn = nbeg; nn < nlim; ++nn) {
    const float4* r = (const float4*)(xs + nn * 32);
    float c0 = 0.f, c1 = 0.f;
#pragma unroll
    for (int k4 = 0; k4 < 8; ++k4) {
      float4 q = r[k4];
      int k = k4 * 4;
      c0 = fmaf(q.x, wreg[k],     c0);
      c1 = fmaf(q.y, wreg[k + 1], c1);
      c0 = fmaf(q.z, wreg[k + 2], c0);
      c1 = fmaf(q.w, wreg[k + 3], c1);
    }
    float o = fmaxf(c0 + c1 + bv, 0.f);
    h[(size_t)(n0 + nn) * 64 + lane] = o;
    hb[(size_t)(n0 + nn) * 64 + lane] = f2bf(o);
  }
}

__global__ void k_set1(int* __restrict__ p, int n) {
  int t = blockIdx.x * blockDim.x + threadIdx.x;
  if (t < n) p[t] = 1;
}

__global__ void k_count(const int* __restrict__ dst, int* __restrict__ cnt, int E) {
  int t = blockIdx.x * blockDim.x + threadIdx.x;
  if (t < E) atomicAdd(&cnt[dst[t]], 1);
}

// Single-block exclusive scan of counter[0..N) -> rowstart[0..N].
__global__ __launch_bounds__(1024) void k_scan(int* __restrict__ counter,
                                               int* __restrict__ rowstart, int N)
{
  __shared__ int wsums[16];
  __shared__ int s_carry;
  int tid = threadIdx.x, lane = tid & 63, wid = tid >> 6;
  if (tid == 0) s_carry = 0;
  __syncthreads();
  for (int base = 0; base < N; base += 1024) {
    int i = base + tid;
    int v = (i < N) ? counter[i] : 0;
    int x = v;
#pragma unroll
    for (int d = 1; d < 64; d <<= 1) {
      int y = __shfl_up(x, d, 64);
      if (lane >= d) x += y;
    }
    if (lane == 63) wsums[wid] = x;
    __syncthreads();
    if (wid == 0) {
      int s = (lane < 16) ? wsums[lane] : 0;
#pragma unroll
      for (int d = 1; d < 16; d <<= 1) {
        int y = __shfl_up(s, d, 64);
        if (lane >= d) s += y;
      }
      if (lane < 16) wsums[lane] = s;
    }
    __syncthreads();
    int carry = s_carry;
    int woff = (wid > 0) ? wsums[wid - 1] : 0;
    int excl = carry + woff + (x - v);
    if (i < N) { rowstart[i] = excl; counter[i] = excl; }
    int total = wsums[15];
    __syncthreads();
    if (tid == 0) s_carry = carry + total;
    __syncthreads();
  }
  if (threadIdx.x == 0) rowstart[N] = s_carry;
}

__global__ void k_fill(const int* __restrict__ src, const int* __restrict__ dst,
                       int* __restrict__ counter, int* __restrict__ srcs, int E, int N)
{
  int t = blockIdx.x * blockDim.x + threadIdx.x;
  if (t >= E + N) return;
  int s, d;
  if (t < E) { s = src[t]; d = dst[t]; } else { s = t - E; d = s; }
  int pos = atomicAdd(&counter[d], 1);
  srcs[pos] = s;
}

// wa[layer][k][q][d] = sum_c Wg[layer][k][q*64+c] * (d? adst : asrc)[layer][q*64+c]
__global__ void k_waprep(const float* __restrict__ Wg, const float* __restrict__ asrc,
                         const float* __restrict__ adst, float* __restrict__ wa, int L)
{
  int t = blockIdx.x * blockDim.x + threadIdx.x;
  if (t >= L * 512) return;
  int layer = t >> 9;
  int rem = t & 511;
  int k = rem >> 3;
  int q = (rem >> 1) & 3;
  int d = rem & 1;
  const float* av = (d ? adst : asrc) + layer * 256 + q * 64;
  const float* wp = Wg + (size_t)layer * 16384 + k * 256 + q * 64;
  float s = 0.f;
#pragma unroll
  for (int c = 0; c < 64; ++c) s = fmaf(wp[c], av[c], s);
  wa[t] = s;
}

// Pack Wfold[K=256][c=64] (= 0.25*Wg[k][head*64+c], K=head*64+k) into MFMA
// B-frag order, hi/lo: whi[((layer*32 + ctile*8 + kstep)*64 + lane)*8 + j]
// holds Wfold[kstep*32 + (lane>>4)*8 + j][ctile*16 + (lane&15)].
__global__ void k_wprep(const float* __restrict__ Wg, unsigned short* __restrict__ whi,
                        unsigned short* __restrict__ wlo, int L)
{
  int t = blockIdx.x * blockDim.x + threadIdx.x;
  if (t >= L * 2048) return;
  int layer = t >> 11;
  int rem = t & 2047;
  int ctile = rem >> 9;
  int kstep = (rem >> 6) & 7;
  int lane = rem & 63;
  int c = ctile * 16 + (lane & 15);
  int Kbase = kstep * 32 + (lane >> 4) * 8;
  size_t obase = (size_t)t * 8;
#pragma unroll
  for (int j = 0; j < 8; ++j) {
    int K = Kbase + j;
    int head = K >> 6, k = K & 63;
    float wv = 0.25f * Wg[(size_t)layer * 16384 + (size_t)k * 256 + head * 64 + c];
    unsigned short hbv = f2bf(wv);
    whi[obase + j] = hbv;
    wlo[obase + j] = f2bf(wv - bf2f(hbv));
  }
}

// als/ald[n,q] = h[n,:] @ wa[:,q,{s,d}]. Thread = (node, q).
__global__ __launch_bounds__(256) void k_att(const float* __restrict__ h,
    const float* __restrict__ wa, float* __restrict__ als,
    float* __restrict__ ald, int N)
{
  int t = blockIdx.x * blockDim.x + threadIdx.x;
  int n = t >> 2, q = t & 3;
  if (n >= N) return;
  const float4* hp = (const float4*)(h + (size_t)n * 64);
  float s = 0.f, d = 0.f;
#pragma unroll
  for (int k4 = 0; k4 < 16; ++k4) {
    float4 hv = hp[k4];
    float ha[4] = {hv.x, hv.y, hv.z, hv.w};
#pragma unroll
    for (int e = 0; e < 4; ++e) {
      float2 wv = *(const float2*)(wa + (size_t)(k4 * 4 + e) * 8 + q * 2);
      s = fmaf(ha[e], wv.x, s);
      d = fmaf(ha[e], wv.y, d);
    }
  }
  als[n * 4 + q] = s;
  ald[n * 4 + q] = d;
}

// One wave per node. Edge-parallel softmax (phase 1, as R5); phase 2 gathers
// bf16 h rows (128B/edge), accumulating 4 per-head sums per channel (lane=ch).
// Writes normalized agg -> aggb[n][head*64+ch] bf16.
__global__ __launch_bounds__(256) void k_agg(const unsigned short* __restrict__ hb,
    const float* __restrict__ als, const float* __restrict__ ald,
    const int* __restrict__ rowstart, const int* __restrict__ srcs,
    unsigned short* __restrict__ aggb, int N)
{
  __shared__ float4 pb[4][64];
  __shared__ int sb[4][64];
  int lane = threadIdx.x & 63;
  int wid = threadIdx.x >> 6;
  int n = blockIdx.x * 4 + wid;
  if (n >= N) return;
  int beg = rowstart[n], end = rowstart[n + 1];
  int deg = end - beg;
  const float4 adv = *(const float4*)(ald + (size_t)n * 4);

  float l0 = 0.f, l1 = 0.f, l2 = 0.f, l3 = 0.f;
  float a0 = 0.f, a1 = 0.f, a2 = 0.f, a3 = 0.f;

  if (deg <= 64) {
    int e = beg + lane;
    int ce = (e < end) ? e : (end - 1);
    int s = srcs[ce];
    float4 av = *(const float4*)(als + (size_t)s * 4);
    float e0 = lrelu02(av.x + adv.x);
    float e1 = lrelu02(av.y + adv.y);
    float e2 = lrelu02(av.z + adv.z);
    float e3 = lrelu02(av.w + adv.w);
    bool act = (e < end);
    float m0 = wave_max(act ? e0 : -1e30f);
    float m1 = wave_max(act ? e1 : -1e30f);
    float m2 = wave_max(act ? e2 : -1e30f);
    float m3 = wave_max(act ? e3 : -1e30f);
    float p0 = act ? __expf(e0 - m0) : 0.f;
    float p1 = act ? __expf(e1 - m1) : 0.f;
    float p2 = act ? __expf(e2 - m2) : 0.f;
    float p3 = act ? __expf(e3 - m3) : 0.f;
    l0 = p0; l1 = p1; l2 = p2; l3 = p3;
    pb[wid][lane] = make_float4(p0, p1, p2, p3);
    sb[wid][lane] = s;
    int j = 0;
    for (; j + 1 < deg; j += 2) {
      float4 pa = pb[wid][j];
      float4 pc = pb[wid][j + 1];
      int sa = sb[wid][j];
      int sc = sb[wid][j + 1];
      float hva = bf2f(hb[(size_t)sa * 64 + lane]);
      float hvc = bf2f(hb[(size_t)sc * 64 + lane]);
      a0 = fmaf(pa.x, hva, a0); a1 = fmaf(pa.y, hva, a1);
      a2 = fmaf(pa.z, hva, a2); a3 = fmaf(pa.w, hva, a3);
      a0 = fmaf(pc.x, hvc, a0); a1 = fmaf(pc.y, hvc, a1);
      a2 = fmaf(pc.z, hvc, a2); a3 = fmaf(pc.w, hvc, a3);
    }
    if (j < deg) {
      float4 p = pb[wid][j];
      int sj = sb[wid][j];
      float hv = bf2f(hb[(size_t)sj * 64 + lane]);
      a0 = fmaf(p.x, hv, a0); a1 = fmaf(p.y, hv, a1);
      a2 = fmaf(p.z, hv, a2); a3 = fmaf(p.w, hv, a3);
    }
  } else {
    float m0 = -1e30f, m1 = -1e30f, m2 = -1e30f, m3 = -1e30f;
    for (int base = beg; base < end; base += 64) {
      int e = base + lane;
      int ce = (e < end) ? e : (end - 1);
      int s = srcs[ce];
      float4 av = *(const float4*)(als + (size_t)s * 4);
      bool act = (e < end);
      m0 = fmaxf(m0, act ? lrelu02(av.x + adv.x) : -1e30f);
      m1 = fmaxf(m1, act ? lrelu02(av.y + adv.y) : -1e30f);
      m2 = fmaxf(m2, act ? lrelu02(av.z + adv.z) : -1e30f);
      m3 = fmaxf(m3, act ? lrelu02(av.w + adv.w) : -1e30f);
    }
    m0 = wave_max(m0); m1 = wave_max(m1); m2 = wave_max(m2); m3 = wave_max(m3);
    for (int base = beg; base < end; base += 64) {
      int e = base + lane;
      int ce = (e < end) ? e : (end - 1);
      int s = srcs[ce];
      float4 av = *(const float4*)(als + (size_t)s * 4);
      bool act = (e < end);
      float p0 = act ? __expf(lrelu02(av.x + adv.x) - m0) : 0.f;
      float p1 = act ? __expf(lrelu02(av.y + adv.y) - m1) : 0.f;
      float p2 = act ? __expf(lrelu02(av.z + adv.z) - m2) : 0.f;
      float p3 = act ? __expf(lrelu02(av.w + adv.w) - m3) : 0.f;
      l0 += p0; l1 += p1; l2 += p2; l3 += p3;
      pb[wid][lane] = make_float4(p0, p1, p2, p3);
      sb[wid][lane] = s;
      int cnt = end - base; if (cnt > 64) cnt = 64;
      for (int j = 0; j < cnt; ++j) {
        float4 p = pb[wid][j];
        int sj = sb[wid][j];
        float hv = bf2f(hb[(size_t)sj * 64 + lane]);
        a0 = fmaf(p.x, hv, a0); a1 = fmaf(p.y, hv, a1);
        a2 = fmaf(p.z, hv, a2); a3 = fmaf(p.w, hv, a3);
      }
    }
  }

  l0 = wave_sum(l0); l1 = wave_sum(l1); l2 = wave_sum(l2); l3 = wave_sum(l3);
  float i0 = 1.f / (l0 + 1e-16f), i1 = 1.f / (l1 + 1e-16f);
  float i2 = 1.f / (l2 + 1e-16f), i3 = 1.f / (l3 + 1e-16f);
  unsigned short* rp = aggb + (size_t)n * 256;
  rp[lane]        = f2bf(a0 * i0);
  rp[64 + lane]   = f2bf(a1 * i1);
  rp[128 + lane]  = f2bf(a2 * i2);
  rp[192 + lane]  = f2bf(a3 * i3);
}

// h' = relu(LN(aggb[N,256] @ Wfold[256,64] + bias)) (+ residual). MFMA with
// bf16 A direct, hi/lo B (2 MFMA per k-step). Block = 16 nodes, wave = ctile.
__global__ __launch_bounds__(256, 4) void k_post(const unsigned short* __restrict__ aggb,
    const unsigned short* __restrict__ whi, const unsigned short* __restrict__ wlo,
    const float* __restrict__ bias, const float* __restrict__ g,
    const float* __restrict__ b, float* __restrict__ h,
    unsigned short* __restrict__ hb, int N, int doRes)
{
  __shared__ float sm[16][68];
  int tid = threadIdx.x, lane = tid & 63, w = tid >> 6;
  int r = lane & 15, kb = lane >> 4;
  int n0 = blockIdx.x * 16;
  int arow = n0 + r; if (arow >= N) arow = N - 1;
  union UB { bf16x8 v; unsigned short u[8]; uint4 q; };
  f32x4 C = {0.f, 0.f, 0.f, 0.f};
#pragma unroll
  for (int ks = 0; ks < 8; ++ks) {
    UB A, Bh, Bl;
    A.q  = *(const uint4*)(aggb + (size_t)arow * 256 + ks * 32 + kb * 8);
    Bh.q = *(const uint4*)(whi + ((size_t)(w * 8 + ks) * 64 + lane) * 8);
    Bl.q = *(const uint4*)(wlo + ((size_t)(w * 8 + ks) * 64 + lane) * 8);
    C = __builtin_amdgcn_mfma_f32_16x16x32_bf16(A.v, Bh.v, C, 0, 0, 0);
    C = __builtin_amdgcn_mfma_f32_16x16x32_bf16(A.v, Bl.v, C, 0, 0, 0);
  }
  float bv = bias[w * 16 + r];
#pragma unroll
  for (int reg = 0; reg < 4; ++reg)
    sm[kb * 4 + reg][w * 16 + r] = C[reg] + bv;
  __syncthreads();
  float gv = g[lane], bbv = b[lane];
#pragma unroll
  for (int rr = 0; rr < 4; ++rr) {
    int row = w * 4 + rr;
    int n = n0 + row;
    if (n >= N) continue;
    float v = sm[row][lane];
    float mu = wave_sum(v) * 0.015625f;
    float dv = v - mu;
    float var = wave_sum(dv * dv) * 0.015625f;
    float y = dv * rsqrtf(var + 1e-5f) * gv + bbv;
    float o = fmaxf(y, 0.f);
    if (doRes) o += h[(size_t)n * 64 + lane];
    h[(size_t)n * 64 + lane] = o;
    hb[(size_t)n * 64 + lane] = f2bf(o);
  }
}

// Fused global_mean_pool + output GEMM (batch sorted -> contiguous ranges).
__global__ __launch_bounds__(256) void k_graph(const float* __restrict__ h,
    const int* __restrict__ batch, const float* __restrict__ Wout,
    const float* __restrict__ bout, float* __restrict__ out, int N)
{
  __shared__ float sm[4][64];
  int g = blockIdx.x;
  int tid = threadIdx.x, lane = tid & 63, wid = tid >> 6;
  int lo = 0, hi = N;
  while (lo < hi) { int mid = (lo + hi) >> 1; if (batch[mid] < g) lo = mid + 1; else hi = mid; }
  int start = lo;
  hi = N;
  while (lo < hi) { int mid = (lo + hi) >> 1; if (batch[mid] < g + 1) lo = mid + 1; else hi = mid; }
  int end = lo;
  float acc = 0.f;
  for (int n = start + wid; n < end; n += 4) acc += h[(size_t)n * 64 + lane];
  sm[wid][lane] = acc;
  __syncthreads();
  if (wid == 0) {
    float s = sm[0][lane] + sm[1][lane] + sm[2][lane] + sm[3][lane];
    float cf = (float)(end - start);
    sm[0][lane] = s / fmaxf(cf, 1.f);
  }
  __syncthreads();
  if (tid < 32) {
    float s = 0.f;
#pragma unroll
    for (int c = 0; c < 64; ++c) s = fmaf(sm[0][c], Wout[c * 32 + tid], s);
    out[g * 32 + tid] = s + bout[tid];
  }
}

extern "C" void kernel_launch(void* const* d_in, const int* in_sizes, int n_in,
                              void* d_out, int out_size, void* d_ws, size_t ws_size,
                              hipStream_t stream) {
  const float* x    = (const float*)d_in[0];
  const int*   ei   = (const int*)d_in[1];
  const int*   batch= (const int*)d_in[2];
  const float* Win  = (const float*)d_in[3];
  const float* bin  = (const float*)d_in[4];
  const float* Wgat = (const float*)d_in[5];
  const float* asrc = (const float*)d_in[6];
  const float* adst = (const float*)d_in[7];
  const float* bgat = (const float*)d_in[8];
  const float* lng  = (const float*)d_in[9];
  const float* lnb  = (const float*)d_in[10];
  const float* Wout = (const float*)d_in[11];
  const float* bout = (const float*)d_in[12];
  float* out = (float*)d_out;

  int N  = in_sizes[0] / 32;
  int E  = in_sizes[1] / 2;
  int NG = out_size / 32;
  int L  = in_sizes[5] / (64 * 256);

  char* w = (char*)d_ws;
  unsigned short* whi = (unsigned short*)w; w += (size_t)L * 16384 * 2;
  unsigned short* wlo = (unsigned short*)w; w += (size_t)L * 16384 * 2;
  float* wa = (float*)w;       w += (size_t)L * 512 * 4;
  unsigned short* aggb = (unsigned short*)w; w += (size_t)N * 256 * 2;
  float* h  = (float*)w;       w += (size_t)N * 64 * 4;
  unsigned short* hb = (unsigned short*)w; w += (size_t)N * 64 * 2;
  float* als= (float*)w;       w += (size_t)N * 4 * 4;
  float* ald= (float*)w;       w += (size_t)N * 4 * 4;
  int* rowstart = (int*)w;     w += (size_t)(N + 1) * 4;
  int* counter  = (int*)w;     w += (size_t)N * 4;
  int* srcs     = (int*)w;     w += (size_t)(E + N) * 4;

  const int* esrc = ei;       // edge_index[0]
  const int* edst = ei + E;   // edge_index[1]

  // weight prep + input layer
  k_wprep<<<(L * 2048 + 255) / 256, 256, 0, stream>>>(Wgat, whi, wlo, L);
  k_waprep<<<(L * 512 + 255) / 256, 256, 0, stream>>>(Wgat, asrc, adst, wa, L);
  k_input<<<(N + 63) / 64, 256, 0, stream>>>(x, Win, bin, h, hb, N);

  // CSR build (dst-grouped), self-loops included via deg init = 1
  k_set1<<<(N + 255) / 256, 256, 0, stream>>>(counter, N);
  k_count<<<(E + 255) / 256, 256, 0, stream>>>(edst, counter, E);
  k_scan<<<1, 1024, 0, stream>>>(counter, rowstart, N);
  k_fill<<<(E + N + 255) / 256, 256, 0, stream>>>(esrc, edst, counter, srcs, E, N);

  for (int i = 0; i < L; ++i) {
    k_att<<<(N * 4 + 255) / 256, 256, 0, stream>>>(h, wa + (size_t)i * 512, als, ald, N);
    k_agg<<<(N + 3) / 4, 256, 0, stream>>>(hb, als, ald, rowstart, srcs, aggb, N);
    k_post<<<(N + 15) / 16, 256, 0, stream>>>(aggb, whi + (size_t)i * 16384,
        wlo + (size_t)i * 16384, bgat + i * 64, lng + i * 64, lnb + i * 64,
        h, hb, N, i > 0 ? 1 : 0);
  }

  // fused mean pool + output GEMM (no atomics; batch is sorted)
  k_graph<<<NG, 256, 0, stream>>>(h, batch, Wout, bout, out, N);
}